// Round 2
// baseline (838.612 us; speedup 1.0000x reference)
//
#include <hip/hip_runtime.h>
#include <hip/hip_cooperative_groups.h>

namespace cg = cooperative_groups;

// B=64, S=512, D=256, VOCAB=50000, NC=10, N_STEPS=10 (h=0.1), BN eval.
// z_final = z0 @ P10 + c10, P10 = M^10, M = 4th-order Taylor of exp(hA), A=W^T.
// Using (W^T)^k = (W^k)^T: A-powers come from W-powers, so the whole prep chain
// is ONE cooperative kernel: W2 | {W3,W4} | M,c1 | M2,c2 | M4,c4 | M8,c8 |
// P10->slab,c10. Conv repack + featbuf zero ride on idle blocks of stage 0.
// k_main: B-fragments read per-wave DIRECTLY from the L2-resident slab into
// registers (slab is already in MFMA B-frag order) -> no B LDS staging, no
// loop barriers; only A-frags go through LDS.

typedef short bf16x8 __attribute__((ext_vector_type(8)));
typedef float f32x4 __attribute__((ext_vector_type(4)));

__device__ __forceinline__ unsigned short f2bf(float f) {
  unsigned u = __float_as_uint(f);
  u += 0x7FFFu + ((u >> 16) & 1u);   // RNE; inputs are normal floats
  return (unsigned short)(u >> 16);
}

// ---------------- fused prep: cooperative, 512 blocks x 256 thr ----------------

__device__ __forceinline__ void matrow256(const float* __restrict__ X,
                                          const float* __restrict__ Y,
                                          float* __restrict__ Z,
                                          int i, int tid, float* xrow) {
  __syncthreads();
  xrow[tid] = X[i * 256 + tid];
  __syncthreads();
  float a0 = 0.f, a1 = 0.f, a2 = 0.f, a3 = 0.f;
#pragma unroll 4
  for (int k = 0; k < 256; k += 4) {
    a0 = fmaf(xrow[k + 0], Y[(k + 0) * 256 + tid], a0);
    a1 = fmaf(xrow[k + 1], Y[(k + 1) * 256 + tid], a1);
    a2 = fmaf(xrow[k + 2], Y[(k + 2) * 256 + tid], a2);
    a3 = fmaf(xrow[k + 3], Y[(k + 3) * 256 + tid], a3);
  }
  Z[i * 256 + tid] = (a0 + a1) + (a2 + a3);
}

// c_out = c_in @ P + c_add (256-vec x 256x256)
__device__ __forceinline__ void vecstage(const float* __restrict__ c_in,
                                         const float* __restrict__ P,
                                         float* __restrict__ c_out,
                                         const float* __restrict__ c_add,
                                         int tid, float* xrow) {
  __syncthreads();
  xrow[tid] = c_in[tid];
  __syncthreads();
  float acc = c_add[tid];
#pragma unroll 4
  for (int k = 0; k < 256; ++k) acc = fmaf(xrow[k], P[k * 256 + tid], acc);
  c_out[tid] = acc;
}

__global__ __launch_bounds__(256) void k_prep(
    const float* __restrict__ W, const float* __restrict__ bode,
    const float* __restrict__ w3, const float* __restrict__ w4c, const float* __restrict__ w5,
    float* __restrict__ ws, unsigned short* __restrict__ slab,
    unsigned* __restrict__ featbuf) {
  float* W2 = ws;
  float* W3 = ws + 65536;
  float* W4 = ws + 131072;
  float* Mm = ws + 196608;
  float* M2 = ws + 262144;
  float* M4 = ws + 327680;
  float* M8 = ws + 393216;
  float* cv = ws + 458752;           // c1 | c2 | c4 | c8 | c10 (256 each)

  cg::grid_group grid = cg::this_grid();
  __shared__ float xrow[256];
  const int tid = threadIdx.x;
  const int blk = blockIdx.x;

  // ---- St0: W2 = W@W (blocks 0-255); conv repack + featbuf zero (256-511)
  if (blk < 256) {
    matrow256(W, W, W2, blk, tid, xrow);
  } else {
    const int base = (blk - 256) * 256 + tid;   // 0..65535
#pragma unroll
    for (int u = 0; u < 6; ++u) {
      int e = base + u * 65536;                 // 0..393215
      int s = e >> 15, r = e & 32767, kd = r >> 7, o = r & 127;
      const float* w; int k, j;
      if (s < 3)      { w = w3;  k = 3; j = s; }
      else if (s < 7) { w = w4c; k = 4; j = s - 3; }
      else            { w = w5;  k = 5; j = s - 7; }
      float val = w[(o * 256 + kd) * k + j];    // w[o][d=kd][j], shape (128,256,k)
      int kc = kd >> 5, quad = (kd >> 3) & 3, q8 = kd & 7;
      slab[s * 32768 + ((kc * 4 + quad) * 128 + o) * 8 + q8] = f2bf(val);
    }
    if (base < 64 * 640) featbuf[base] = 0u;
  }
  __threadfence();
  grid.sync();

  // ---- St1: W3 = W@W2 (0-255); W4 = W2@W2 (256-511)
  if (blk < 256) matrow256(W, W2, W3, blk, tid, xrow);
  else           matrow256(W2, W2, W4, blk - 256, tid, xrow);
  __threadfence();
  grid.sync();

  // ---- St2: M = I + hA + A2/2 + A3/6 + A4/24  (A^k = 0.1^k (W^k)^T); c1
  if (blk < 256) {
    int i = blk, j = tid;
    float m = ((i == j) ? 1.f : 0.f)
            + 0.1f * W[j * 256 + i]
            + (0.01f / 2.f)   * W2[j * 256 + i]
            + (0.001f / 6.f)  * W3[j * 256 + i]
            + (0.0001f / 24.f)* W4[j * 256 + i];
    Mm[i * 256 + j] = m;
  } else if (blk == 256) {
    // c1[j] = 0.1*(b[j] + sum_k b[k]*(0.05 W[j][k] + 0.01/6 W2[j][k] + 0.001/24 W3[j][k]))
    __syncthreads();
    xrow[tid] = bode[tid];
    __syncthreads();
    int j = tid;
    float acc = xrow[j];
    for (int k = 0; k < 256; ++k) {
      float q = 0.05f * W[j * 256 + k] + (0.01f / 6.f) * W2[j * 256 + k]
              + (0.001f / 24.f) * W3[j * 256 + k];
      acc = fmaf(xrow[k], q, acc);
    }
    cv[j] = 0.1f * acc;
  }
  __threadfence();
  grid.sync();

  // ---- St3: M2 = M@M; c2 = c1@M + c1
  if (blk < 256) matrow256(Mm, Mm, M2, blk, tid, xrow);
  else if (blk == 256) vecstage(cv, Mm, cv + 256, cv, tid, xrow);
  __threadfence();
  grid.sync();

  // ---- St4: M4 = M2@M2; c4 = c2@M2 + c2
  if (blk < 256) matrow256(M2, M2, M4, blk, tid, xrow);
  else if (blk == 256) vecstage(cv + 256, M2, cv + 512, cv + 256, tid, xrow);
  __threadfence();
  grid.sync();

  // ---- St5: M8 = M4@M4; c8 = c4@M4 + c4
  if (blk < 256) matrow256(M4, M4, M8, blk, tid, xrow);
  else if (blk == 256) vecstage(cv + 512, M4, cv + 768, cv + 512, tid, xrow);
  __threadfence();
  grid.sync();

  // ---- St6: P10 row = (M8@M2)[blk], repacked straight to bf16 slab; c10 = c8@M2 + c2
  if (blk < 256) {
    __syncthreads();
    xrow[tid] = M8[blk * 256 + tid];
    __syncthreads();
    float a0 = 0.f, a1 = 0.f, a2 = 0.f, a3 = 0.f;
#pragma unroll 4
    for (int k = 0; k < 256; k += 4) {
      a0 = fmaf(xrow[k + 0], M2[(k + 0) * 256 + tid], a0);
      a1 = fmaf(xrow[k + 1], M2[(k + 1) * 256 + tid], a1);
      a2 = fmaf(xrow[k + 2], M2[(k + 2) * 256 + tid], a2);
      a3 = fmaf(xrow[k + 3], M2[(k + 3) * 256 + tid], a3);
    }
    float val = (a0 + a1) + (a2 + a3);          // P10[blk][tid]
    int i = blk, o = tid;
    int kc = i >> 5, quad = (i >> 3) & 3, q8 = i & 7;
    int s = 12 + (o >> 7);
    slab[s * 32768 + ((kc * 4 + quad) * 128 + (o & 127)) * 8 + q8] = f2bf(val);
  } else if (blk == 256) {
    vecstage(cv + 768, M2, cv + 1024, cv + 256, tid, xrow);
  }
}

// ---------------- fused main kernel ----------------
// grid 512 = 64 batches x 8 t-chunks of 64. 256 threads = 4 waves.
// LDS: only the X tile (68 x 264 bf16). B-fragments are read per-wave directly
// from the slab (L2-resident, already in MFMA B-frag order) with a 1-pair
// software pipeline. No barriers in the main loop.

__global__ __launch_bounds__(256, 2) void k_main(
    const int* __restrict__ ids, const float* __restrict__ emb,
    const unsigned short* __restrict__ slab, const float* __restrict__ ctot,
    const float* __restrict__ b3, const float* __restrict__ g3, const float* __restrict__ be3,
    const float* __restrict__ b4, const float* __restrict__ g4, const float* __restrict__ be4,
    const float* __restrict__ b5, const float* __restrict__ g5, const float* __restrict__ be5,
    unsigned* __restrict__ featbuf) {
  __shared__ alignas(16) unsigned short Xt[68 * 264];
  __shared__ int ids_s[68];
  const int tid = threadIdx.x;
  const int blk = blockIdx.x;
  const int b = blk >> 3;
  const int t0 = (blk & 7) * 64;
  const int lane = tid & 63;
  const int wave = tid >> 6;
  const int m15 = lane & 15;
  const int quad = lane >> 4;

  if (tid < 68) {
    int t = t0 + tid;
    ids_s[tid] = (t < 512) ? ids[b * 512 + t] : -1;
  }
  __syncthreads();
  // gather + fp32->bf16 X tile (rows beyond S zero-filled)
  for (int i = tid; i < 68 * 64; i += 256) {
    int row = i >> 6, s4 = i & 63;
    uint2 v = make_uint2(0u, 0u);
    int id = ids_s[row];
    if (id >= 0) {
      const float4 f = *(const float4*)(emb + (size_t)id * 256 + s4 * 4);
      v.x = (unsigned)f2bf(f.x) | ((unsigned)f2bf(f.y) << 16);
      v.y = (unsigned)f2bf(f.z) | ((unsigned)f2bf(f.w) << 16);
    }
    *(uint2*)&Xt[row * 264 + s4 * 4] = v;
  }
  __syncthreads();  // Xt ready; no further barriers

  // per-lane B-fragment bases (bf16 units); frag(e,kc2,nt) = fb[nt] + e*8192 + kc2*4096
  const unsigned short* fb0 = slab + ((size_t)quad * 128 + (wave * 2 + 0) * 16 + m15) * 8;
  const unsigned short* fb1 = fb0 + 128;   // nt=1: +16*8

  bf16x8 fA[4], fB[4];   // [kc2*2+nt]
#pragma unroll
  for (int q = 0; q < 4; ++q) {
    fA[q] = *(const bf16x8*)(((q & 1) ? fb1 : fb0) + (q >> 1) * 4096);
    fB[q] = *(const bf16x8*)(((q & 1) ? fb1 : fb0) + 8192 + (q >> 1) * 4096);
  }

  f32x4 acc[4][2];
#pragma unroll
  for (int mt = 0; mt < 4; ++mt)
#pragma unroll
    for (int nt = 0; nt < 2; ++nt) acc[mt][nt] = (f32x4){0.f, 0.f, 0.f, 0.f};

#define ENTRY(KCQ, FR)                                                          \
  {                                                                             \
    _Pragma("unroll")                                                           \
    for (int kc2 = 0; kc2 < 2; ++kc2) {                                         \
      const int kd0 = ((KCQ) * 2 + kc2) * 32 + quad * 8;                        \
      bf16x8 af[4];                                                             \
      _Pragma("unroll")                                                         \
      for (int mt = 0; mt < 4; ++mt)                                            \
        af[mt] = *(const bf16x8*)&Xt[(shift + mt * 16 + m15) * 264 + kd0];      \
      _Pragma("unroll")                                                         \
      for (int mt = 0; mt < 4; ++mt) {                                          \
        acc[mt][0] = __builtin_amdgcn_mfma_f32_16x16x32_bf16(af[mt], FR[kc2 * 2 + 0], acc[mt][0], 0, 0, 0); \
        acc[mt][1] = __builtin_amdgcn_mfma_f32_16x16x32_bf16(af[mt], FR[kc2 * 2 + 1], acc[mt][1], 0, 0, 0); \
      }                                                                         \
    }                                                                           \
  }

  for (int ep = 0; ep < 28; ++ep) {
    const int e0 = ep * 2;
    const int slice = e0 >> 2;             // e0,e0+1 share slice
    const int shift = (slice < 3) ? slice
                    : (slice < 7) ? (slice - 3)
                    : (slice < 12) ? (slice - 7) : 0;
    const int kcq0 = e0 & 3;

    ENTRY(kcq0, fA);
    if (ep < 27) {
      const int eo = (e0 + 2) * 8192;
#pragma unroll
      for (int q = 0; q < 4; ++q)
        fA[q] = *(const bf16x8*)(((q & 1) ? fb1 : fb0) + eo + (q >> 1) * 4096);
    }
    ENTRY(kcq0 + 1, fB);
    if (ep < 27) {
      const int eo = (e0 + 3) * 8192;
#pragma unroll
      for (int q = 0; q < 4; ++q)
        fB[q] = *(const bf16x8*)(((q & 1) ? fb1 : fb0) + eo + (q >> 1) * 4096);
    }

    // epilogue at group boundaries: ep 5 (conv3), 13 (conv4), 23 (conv5),
    // 25 (node lo), 27 (node hi)
    const int g = (ep == 5) ? 0 : (ep == 13) ? 1 : (ep == 23) ? 2
                : (ep == 25) ? 3 : (ep == 27) ? 4 : -1;
    if (g >= 0) {
      if (g < 3) {
        const int kk = g + 3;
        const float* bb  = (g == 0) ? b3 : (g == 1) ? b4 : b5;
        const float* gg  = (g == 0) ? g3 : (g == 1) ? g4 : g5;
        const float* bbe = (g == 0) ? be3 : (g == 1) ? be4 : be5;
        const int off = 256 + g * 128;     // feats: [node 256][p3 128][p4 128][p5 128]
        const int tmax = 512 - kk;
#pragma unroll
        for (int nt = 0; nt < 2; ++nt) {
          const int n = (wave * 2 + nt) * 16 + m15;
          const float sc = gg[n] * 0.9999950000375f;  // g * 1/sqrt(1+1e-5)
          const float sh = fmaf(sc, bb[n], bbe[n]);
          float mx = 0.f;  // relu floor doubles as init
#pragma unroll
          for (int mt = 0; mt < 4; ++mt)
#pragma unroll
            for (int r = 0; r < 4; ++r) {
              const int t = t0 + mt * 16 + quad * 4 + r;
              const float v = fmaf(sc, acc[mt][nt][r], sh);
              if (t <= tmax) mx = fmaxf(mx, v);
            }
          mx = fmaxf(mx, __shfl_xor(mx, 16));
          mx = fmaxf(mx, __shfl_xor(mx, 32));
          if (quad == 0) atomicMax(&featbuf[b * 640 + off + n], __float_as_uint(mx));
        }
      } else {
        const int base = (g == 3) ? 0 : 128;
#pragma unroll
        for (int nt = 0; nt < 2; ++nt) {
          const int n = (wave * 2 + nt) * 16 + m15;
          const float ct = ctot[base + n];
          float mx = -3.4e38f;
#pragma unroll
          for (int mt = 0; mt < 4; ++mt)
#pragma unroll
            for (int r = 0; r < 4; ++r)
              mx = fmaxf(mx, acc[mt][nt][r] + ct);
          mx = fmaxf(mx, __shfl_xor(mx, 16));
          mx = fmaxf(mx, __shfl_xor(mx, 32));
          if (quad == 0) {
            unsigned bits = __float_as_uint(mx);
            unsigned key = (bits & 0x80000000u) ? ~bits : (bits | 0x80000000u);  // order-preserving
            atomicMax(&featbuf[b * 640 + base + n], key);
          }
        }
      }
      // reset accumulators for the next group
#pragma unroll
      for (int mt = 0; mt < 4; ++mt)
#pragma unroll
        for (int nt = 0; nt < 2; ++nt) acc[mt][nt] = (f32x4){0.f, 0.f, 0.f, 0.f};
    }
  }
#undef ENTRY
}

// ---------------- classifier ----------------
__global__ void k_fin(const unsigned* __restrict__ featbuf, const float* __restrict__ wc,
                      const float* __restrict__ bc, float* __restrict__ out) {
  int b = blockIdx.x, lane = threadIdx.x;  // 64 threads = 1 wave
  float p[10];
#pragma unroll
  for (int c = 0; c < 10; ++c) p[c] = 0.f;
  for (int f = lane; f < 640; f += 64) {
    unsigned u = featbuf[b * 640 + f];
    float v;
    if (f < 256) v = (u & 0x80000000u) ? __uint_as_float(u ^ 0x80000000u) : __uint_as_float(~u);
    else v = __uint_as_float(u);
#pragma unroll
    for (int c = 0; c < 10; ++c) p[c] = fmaf(v, wc[c * 640 + f], p[c]);
  }
#pragma unroll
  for (int c = 0; c < 10; ++c) {
    float s = p[c];
#pragma unroll
    for (int off = 32; off > 0; off >>= 1) s += __shfl_down(s, off);
    if (lane == 0) out[b * 10 + c] = s + bc[c];
  }
}

// ---------------- launcher ----------------
extern "C" void kernel_launch(void* const* d_in, const int* in_sizes, int n_in,
                              void* d_out, int out_size, void* d_ws, size_t ws_size,
                              hipStream_t stream) {
  (void)in_sizes; (void)n_in; (void)out_size; (void)ws_size;
  const int*   ids  = (const int*)d_in[0];
  const float* emb  = (const float*)d_in[1];
  const float* W    = (const float*)d_in[2];
  const float* bode = (const float*)d_in[3];
  const float* w3   = (const float*)d_in[4];
  const float* b3   = (const float*)d_in[5];
  const float* g3   = (const float*)d_in[6];
  const float* be3  = (const float*)d_in[7];
  const float* w4   = (const float*)d_in[8];
  const float* b4   = (const float*)d_in[9];
  const float* g4   = (const float*)d_in[10];
  const float* be4  = (const float*)d_in[11];
  const float* w5   = (const float*)d_in[12];
  const float* b5   = (const float*)d_in[13];
  const float* g5   = (const float*)d_in[14];
  const float* be5  = (const float*)d_in[15];
  const float* wc   = (const float*)d_in[16];
  const float* bc   = (const float*)d_in[17];
  float* out = (float*)d_out;

  float* wsf = (float*)d_ws;
  // ws layout (floats): W2 0 | W3 65536 | W4 131072 | M 196608 | M2 262144 |
  // M4 327680 | M8 393216 | cv 458752 (c1,c2,c4,c8,c10) | slab 460032 (bf16) |
  // featbuf 689408
  unsigned short* slab = (unsigned short*)(wsf + 460032);   // 14*32768 bf16
  unsigned* featbuf = (unsigned*)(wsf + 689408);            // 64*640 uint keys
  const float* c10 = wsf + 459776;

  void* args[] = {(void*)&W, (void*)&bode, (void*)&w3, (void*)&w4, (void*)&w5,
                  (void*)&wsf, (void*)&slab, (void*)&featbuf};
  hipLaunchCooperativeKernel((const void*)k_prep, dim3(512), dim3(256), args, 0, stream);

  hipLaunchKernelGGL(k_main, dim3(512), dim3(256), 0, stream,
                     ids, emb, slab, c10,
                     b3, g3, be3, b4, g4, be4, b5, g5, be5, featbuf);
  hipLaunchKernelGGL(k_fin, dim3(64), dim3(64), 0, stream, featbuf, wc, bc, out);
}

// Round 3
// 256.624 us; speedup vs baseline: 3.2679x; 3.2679x over previous
//
#include <hip/hip_runtime.h>

// B=64, S=512, D=256, VOCAB=50000, NC=10, N_STEPS=10 (h=0.1), BN eval.
// z_final = z0 @ P10 + c10, P10 = M^10, M = 4th-order Taylor of exp(hA), A=W^T.
// Transpose trick: M = N^T with N = I + 0.1W + 0.005W^2 + (1e-3/6)W^3 + (1e-4/24)W^4,
// so P10 = (N^10)^T and the whole power chain runs in W/N space with coalesced
// row-GEMMs; the transpose is absorbed into the (already scattered) slab repack.
// Prep = 7 stream-ordered dispatches (grid.sync was ~100us/sync -> removed):
//   k_w2rep: W2 = W@W  + conv repack + featbuf zero (spare blocks)
//   k_w34:   W3 = W@W2 | W4 = W2@W2
//   k_buildN: N elementwise | c1 row-dot
//   k_pow x4: N2, N4, N8, N10->slab (+ c2, c4, c8, c10 on block 256)
// Each GEMM row-block keeps 16 loads in flight per thread (bv[16], unroll-4
// outer) -> latency-bound time ~2-4us/dispatch instead of ~17us.
// k_main: round-1 proven version (double-buffered B tile, 63.7us).

typedef short bf16x8 __attribute__((ext_vector_type(8)));
typedef float f32x4 __attribute__((ext_vector_type(4)));

__device__ __forceinline__ unsigned short f2bf(float f) {
  unsigned u = __float_as_uint(f);
  u += 0x7FFFu + ((u >> 16) & 1u);   // RNE; inputs are normal floats
  return (unsigned short)(u >> 16);
}

// row i of X@Y, one block of 256 threads; thread tid owns column tid.
// 16 loads in flight per thread per group; outer unroll 4 -> deep window.
__device__ __forceinline__ float gemmrow_val(const float* __restrict__ X,
                                             const float* __restrict__ Y,
                                             int i, int tid, float* xrow) {
  xrow[tid] = X[i * 256 + tid];
  __syncthreads();
  float a0 = 0.f, a1 = 0.f, a2 = 0.f, a3 = 0.f;
#pragma unroll 4
  for (int k = 0; k < 256; k += 16) {
    float bv[16];
#pragma unroll
    for (int u = 0; u < 16; ++u) bv[u] = Y[(k + u) * 256 + tid];
#pragma unroll
    for (int u = 0; u < 16; u += 4) {
      a0 = fmaf(xrow[k + u + 0], bv[u + 0], a0);
      a1 = fmaf(xrow[k + u + 1], bv[u + 1], a1);
      a2 = fmaf(xrow[k + u + 2], bv[u + 2], a2);
      a3 = fmaf(xrow[k + u + 3], bv[u + 3], a3);
    }
  }
  return (a0 + a1) + (a2 + a3);
}

// cout[j] = sum_k cin[k] * Ymat[j][k] + cadd[j]   (one block; per-thread row scan)
__device__ __forceinline__ void vec_rowdot(const float* __restrict__ cin,
                                           const float* __restrict__ Ymat,
                                           const float* __restrict__ cadd,
                                           float* __restrict__ cout,
                                           int tid, float* xrow) {
  xrow[tid] = cin[tid];
  __syncthreads();
  float acc = cadd[tid];
  const float* row = Ymat + (size_t)tid * 256;
#pragma unroll 4
  for (int k = 0; k < 256; k += 16) {
    float bv[16];
#pragma unroll
    for (int u = 0; u < 16; ++u) bv[u] = row[k + u];
#pragma unroll
    for (int u = 0; u < 16; ++u) acc = fmaf(xrow[k + u], bv[u], acc);
  }
  cout[tid] = acc;
}

// ---- dispatch 1: W2 = W@W (blocks 0-255); conv repack + featbuf zero (256-639)
__global__ __launch_bounds__(256) void k_w2rep(
    const float* __restrict__ W, float* __restrict__ W2,
    const float* __restrict__ w3, const float* __restrict__ w4c, const float* __restrict__ w5,
    unsigned short* __restrict__ slab, unsigned* __restrict__ featbuf) {
  __shared__ float xrow[256];
  const int tid = threadIdx.x, blk = blockIdx.x;
  if (blk < 256) {
    W2[blk * 256 + tid] = gemmrow_val(W, W, blk, tid, xrow);
  } else {
    const int base = (blk - 256) * 256 + tid;   // 0..98303
#pragma unroll
    for (int u = 0; u < 4; ++u) {
      int e = base + u * 98304;                 // covers 0..393215 = 12*32768
      int s = e >> 15, r = e & 32767, kd = r >> 7, o = r & 127;
      const float* w; int k, j;
      if (s < 3)      { w = w3;  k = 3; j = s; }
      else if (s < 7) { w = w4c; k = 4; j = s - 3; }
      else            { w = w5;  k = 5; j = s - 7; }
      float val = w[(o * 256 + kd) * k + j];    // w[o][d=kd][j], shape (128,256,k)
      int kc = kd >> 5, quad = (kd >> 3) & 3, q8 = kd & 7;
      slab[s * 32768 + ((kc * 4 + quad) * 128 + o) * 8 + q8] = f2bf(val);
    }
    if (base < 64 * 640) featbuf[base] = 0u;
  }
}

// ---- dispatch 2: W3 = W@W2 (0-255) | W4 = W2@W2 (256-511)
__global__ __launch_bounds__(256) void k_w34(
    const float* __restrict__ W, const float* __restrict__ W2,
    float* __restrict__ W3, float* __restrict__ W4) {
  __shared__ float xrow[256];
  const int tid = threadIdx.x, blk = blockIdx.x;
  if (blk < 256) W3[blk * 256 + tid] = gemmrow_val(W, W2, blk, tid, xrow);
  else           W4[(blk - 256) * 256 + tid] = gemmrow_val(W2, W2, blk - 256, tid, xrow);
}

// ---- dispatch 3: N = I + 0.1W + 0.005W2 + (1e-3/6)W3 + (1e-4/24)W4 | c1
__global__ __launch_bounds__(256) void k_buildN(
    const float* __restrict__ W, const float* __restrict__ W2,
    const float* __restrict__ W3, const float* __restrict__ W4,
    float* __restrict__ N, const float* __restrict__ bode, float* __restrict__ c1) {
  __shared__ float xrow[256];
  const int tid = threadIdx.x, blk = blockIdx.x;
  if (blk < 256) {
    int e = blk * 256 + tid;
    float v = ((blk == tid) ? 1.f : 0.f)
            + 0.1f * W[e] + 0.005f * W2[e]
            + (0.001f / 6.f) * W3[e] + (0.0001f / 24.f) * W4[e];
    N[e] = v;
  } else {
    // c1[j] = 0.1*(b[j] + sum_k b[k]*(0.05 W[j,k] + (0.01/6) W2[j,k] + (1e-3/24) W3[j,k]))
    xrow[tid] = bode[tid];
    __syncthreads();
    const int j = tid;
    float acc = xrow[j];
    const float* r1 = W  + (size_t)j * 256;
    const float* r2 = W2 + (size_t)j * 256;
    const float* r3 = W3 + (size_t)j * 256;
#pragma unroll 4
    for (int k = 0; k < 256; k += 8) {
      float b1[8], b2[8], b3v[8];
#pragma unroll
      for (int u = 0; u < 8; ++u) { b1[u] = r1[k + u]; b2[u] = r2[k + u]; b3v[u] = r3[k + u]; }
#pragma unroll
      for (int u = 0; u < 8; ++u) {
        float q = 0.05f * b1[u] + (0.01f / 6.f) * b2[u] + (0.001f / 24.f) * b3v[u];
        acc = fmaf(xrow[k + u], q, acc);
      }
    }
    c1[j] = 0.1f * acc;
  }
}

// ---- dispatches 4-7: Z = X@Y (0-255); Z==nullptr -> write N10 transposed into slab
//      block 256: cout = cin @ Y^T-rowdot + cadd
__global__ __launch_bounds__(256) void k_pow(
    const float* __restrict__ X, const float* __restrict__ Y,
    float* __restrict__ Z, unsigned short* __restrict__ slab,
    const float* __restrict__ cin, const float* __restrict__ cadd,
    float* __restrict__ cout) {
  __shared__ float xrow[256];
  const int tid = threadIdx.x, blk = blockIdx.x;
  if (blk < 256) {
    float v = gemmrow_val(X, Y, blk, tid, xrow);
    if (Z) {
      Z[blk * 256 + tid] = v;
    } else {
      // v = N10[o=blk][kd=tid] = P10[kd][o]; slab node layout, s = 12 + (o>>7)
      int o = blk, kd = tid;
      int kc = kd >> 5, quad = (kd >> 3) & 3, q8 = kd & 7;
      slab[(12 + (o >> 7)) * 32768 + ((kc * 4 + quad) * 128 + (o & 127)) * 8 + q8] = f2bf(v);
    }
  } else {
    vec_rowdot(cin, Y, cadd, cout, tid, xrow);
  }
}

// ---------------- fused main kernel (round-1 proven, 63.7us) ----------------
// grid 512 = 64 batches x 8 t-chunks of 64. 256 threads = 4 waves.
// LDS: X tile 68 x 264 bf16; B tile 2 x 16 KB double-buffered.
// Per iteration: issue next-stage loads -> 16 MFMA from Bt[cur] -> epilogue at
// group ends -> ds_write Bt[cur^1] -> ONE barrier.

__global__ __launch_bounds__(256, 2) void k_main(
    const int* __restrict__ ids, const float* __restrict__ emb,
    const unsigned short* __restrict__ slab, const float* __restrict__ ctot,
    const float* __restrict__ b3, const float* __restrict__ g3, const float* __restrict__ be3,
    const float* __restrict__ b4, const float* __restrict__ g4, const float* __restrict__ be4,
    const float* __restrict__ b5, const float* __restrict__ g5, const float* __restrict__ be5,
    unsigned* __restrict__ featbuf) {
  __shared__ alignas(16) unsigned short Xt[68 * 264];
  __shared__ alignas(16) unsigned short Bt[2][8192];
  __shared__ int ids_s[68];
  const int tid = threadIdx.x;
  const int blk = blockIdx.x;
  const int b = blk >> 3;
  const int t0 = (blk & 7) * 64;
  const int lane = tid & 63;
  const int wave = tid >> 6;
  const int m15 = lane & 15;
  const int quad = lane >> 4;

  if (tid < 68) {
    int t = t0 + tid;
    ids_s[tid] = (t < 512) ? ids[b * 512 + t] : -1;
  }
  __syncthreads();

  // issue entry-0 B-stage loads first; latency hides under the X gather
  const uint4* slab4 = (const uint4*)slab;
  uint4 st0 = slab4[tid];
  uint4 st1 = slab4[tid + 256];
  uint4 st2 = slab4[tid + 512];
  uint4 st3 = slab4[tid + 768];

  // gather + fp32->bf16 X tile (rows beyond S zero-filled)
  for (int i = tid; i < 68 * 64; i += 256) {
    int row = i >> 6, s4 = i & 63;
    uint2 v = make_uint2(0u, 0u);
    int id = ids_s[row];
    if (id >= 0) {
      const float4 f = *(const float4*)(emb + (size_t)id * 256 + s4 * 4);
      v.x = (unsigned)f2bf(f.x) | ((unsigned)f2bf(f.y) << 16);
      v.y = (unsigned)f2bf(f.z) | ((unsigned)f2bf(f.w) << 16);
    }
    *(uint2*)&Xt[row * 264 + s4 * 4] = v;
  }
  {
    uint4* dst = (uint4*)Bt[0] + tid;
    dst[0] = st0; dst[256] = st1; dst[512] = st2; dst[768] = st3;
  }
  __syncthreads();  // Xt + Bt[0] ready

  f32x4 acc[4][2];
#pragma unroll
  for (int mt = 0; mt < 4; ++mt)
#pragma unroll
    for (int nt = 0; nt < 2; ++nt) acc[mt][nt] = (f32x4){0.f, 0.f, 0.f, 0.f};

  int cur = 0;
  for (int e = 0; e < 56; ++e) {
    const int slice = e >> 2;
    const int kcq = e & 3;
    // conv shift = ji within group; node slices shift 0
    const int shift = (slice < 3) ? slice
                    : (slice < 7) ? (slice - 3)
                    : (slice < 12) ? (slice - 7) : 0;

    // prefetch next stage into regs (no wait until the ds_write below)
    if (e < 55) {
      const uint4* src = slab4 + (((e + 1) >> 2) * 4096 + ((e + 1) & 3) * 1024) + tid;
      st0 = src[0]; st1 = src[256]; st2 = src[512]; st3 = src[768];
    }

    const unsigned short* Bc = Bt[cur];
#pragma unroll
    for (int kc2 = 0; kc2 < 2; ++kc2) {
      const int kd0 = (kcq * 2 + kc2) * 32 + quad * 8;
      bf16x8 af[4];
#pragma unroll
      for (int mt = 0; mt < 4; ++mt)
        af[mt] = *(const bf16x8*)&Xt[(shift + mt * 16 + m15) * 264 + kd0];
#pragma unroll
      for (int nt = 0; nt < 2; ++nt) {
        const bf16x8 bfr =
            *(const bf16x8*)&Bc[((kc2 * 4 + quad) * 128 + (wave * 2 + nt) * 16 + m15) * 8];
#pragma unroll
        for (int mt = 0; mt < 4; ++mt)
          acc[mt][nt] = __builtin_amdgcn_mfma_f32_16x16x32_bf16(af[mt], bfr, acc[mt][nt], 0, 0, 0);
      }
    }

    // epilogue at group boundaries (registers + shuffles + atomics only)
    if (kcq == 3) {
      const int g = (e == 11) ? 0 : (e == 27) ? 1 : (e == 47) ? 2
                  : (e == 51) ? 3 : (e == 55) ? 4 : -1;
      if (g >= 0) {
        if (g < 3) {
          const int kk = g + 3;
          const float* bb  = (g == 0) ? b3 : (g == 1) ? b4 : b5;
          const float* gg  = (g == 0) ? g3 : (g == 1) ? g4 : g5;
          const float* bbe = (g == 0) ? be3 : (g == 1) ? be4 : be5;
          const int off = 256 + g * 128;   // feats: [node 256][p3 128][p4 128][p5 128]
          const int tmax = 512 - kk;
#pragma unroll
          for (int nt = 0; nt < 2; ++nt) {
            const int n = (wave * 2 + nt) * 16 + m15;
            const float sc = gg[n] * 0.9999950000375f;  // g * 1/sqrt(1+1e-5)
            const float sh = fmaf(sc, bb[n], bbe[n]);
            float mx = 0.f;  // relu floor doubles as init
#pragma unroll
            for (int mt = 0; mt < 4; ++mt)
#pragma unroll
              for (int r = 0; r < 4; ++r) {
                const int t = t0 + mt * 16 + quad * 4 + r;
                const float v = fmaf(sc, acc[mt][nt][r], sh);
                if (t <= tmax) mx = fmaxf(mx, v);
              }
            mx = fmaxf(mx, __shfl_xor(mx, 16));
            mx = fmaxf(mx, __shfl_xor(mx, 32));
            if (quad == 0) atomicMax(&featbuf[b * 640 + off + n], __float_as_uint(mx));
          }
        } else {
          const int base = (g == 3) ? 0 : 128;
#pragma unroll
          for (int nt = 0; nt < 2; ++nt) {
            const int n = (wave * 2 + nt) * 16 + m15;
            const float ct = ctot[base + n];
            float mx = -3.4e38f;
#pragma unroll
            for (int mt = 0; mt < 4; ++mt)
#pragma unroll
              for (int r = 0; r < 4; ++r)
                mx = fmaxf(mx, acc[mt][nt][r] + ct);
            mx = fmaxf(mx, __shfl_xor(mx, 16));
            mx = fmaxf(mx, __shfl_xor(mx, 32));
            if (quad == 0) {
              unsigned bits = __float_as_uint(mx);
              unsigned key = (bits & 0x80000000u) ? ~bits : (bits | 0x80000000u);  // order-preserving
              atomicMax(&featbuf[b * 640 + base + n], key);
            }
          }
        }
        // reset accumulators for the next group
#pragma unroll
        for (int mt = 0; mt < 4; ++mt)
#pragma unroll
          for (int nt = 0; nt < 2; ++nt) acc[mt][nt] = (f32x4){0.f, 0.f, 0.f, 0.f};
      }
    }

    // write next stage into the other buffer (vmcnt drain lands here,
    // after ~300+ cycles of MFMA/ds_read work), then a single barrier
    if (e < 55) {
      uint4* dst = (uint4*)Bt[cur ^ 1] + tid;
      dst[0] = st0; dst[256] = st1; dst[512] = st2; dst[768] = st3;
    }
    __syncthreads();
    cur ^= 1;
  }
}

// ---------------- classifier ----------------
__global__ void k_fin(const unsigned* __restrict__ featbuf, const float* __restrict__ wc,
                      const float* __restrict__ bc, float* __restrict__ out) {
  int b = blockIdx.x, lane = threadIdx.x;  // 64 threads = 1 wave
  float p[10];
#pragma unroll
  for (int c = 0; c < 10; ++c) p[c] = 0.f;
  for (int f = lane; f < 640; f += 64) {
    unsigned u = featbuf[b * 640 + f];
    float v;
    if (f < 256) v = (u & 0x80000000u) ? __uint_as_float(u ^ 0x80000000u) : __uint_as_float(~u);
    else v = __uint_as_float(u);
#pragma unroll
    for (int c = 0; c < 10; ++c) p[c] = fmaf(v, wc[c * 640 + f], p[c]);
  }
#pragma unroll
  for (int c = 0; c < 10; ++c) {
    float s = p[c];
#pragma unroll
    for (int off = 32; off > 0; off >>= 1) s += __shfl_down(s, off);
    if (lane == 0) out[b * 10 + c] = s + bc[c];
  }
}

// ---------------- launcher ----------------
extern "C" void kernel_launch(void* const* d_in, const int* in_sizes, int n_in,
                              void* d_out, int out_size, void* d_ws, size_t ws_size,
                              hipStream_t stream) {
  (void)in_sizes; (void)n_in; (void)out_size; (void)ws_size;
  const int*   ids  = (const int*)d_in[0];
  const float* emb  = (const float*)d_in[1];
  const float* W    = (const float*)d_in[2];
  const float* bode = (const float*)d_in[3];
  const float* w3   = (const float*)d_in[4];
  const float* b3   = (const float*)d_in[5];
  const float* g3   = (const float*)d_in[6];
  const float* be3  = (const float*)d_in[7];
  const float* w4   = (const float*)d_in[8];
  const float* b4   = (const float*)d_in[9];
  const float* g4   = (const float*)d_in[10];
  const float* be4  = (const float*)d_in[11];
  const float* w5   = (const float*)d_in[12];
  const float* b5   = (const float*)d_in[13];
  const float* g5   = (const float*)d_in[14];
  const float* be5  = (const float*)d_in[15];
  const float* wc   = (const float*)d_in[16];
  const float* bc   = (const float*)d_in[17];
  float* out = (float*)d_out;

  float* wsf = (float*)d_ws;
  // ws layout (floats): W2 0 | W3 65536 | W4 131072 | N 196608 | N2 262144 |
  // N4 327680 | N8 393216 | cv 458752 (c1,c2,c4,c8,c10 x256) | slab 460032 (bf16) |
  // featbuf 689408
  float* W2 = wsf;
  float* W3 = wsf + 65536;
  float* W4 = wsf + 131072;
  float* N  = wsf + 196608;
  float* N2 = wsf + 262144;
  float* N4 = wsf + 327680;
  float* N8 = wsf + 393216;
  float* cv = wsf + 458752;
  unsigned short* slab = (unsigned short*)(wsf + 460032);   // 14*32768 bf16
  unsigned* featbuf = (unsigned*)(wsf + 689408);            // 64*640 uint keys
  const float* c10 = cv + 1024;

  hipLaunchKernelGGL(k_w2rep, dim3(640), dim3(256), 0, stream, W, W2, w3, w4, w5, slab, featbuf);
  hipLaunchKernelGGL(k_w34, dim3(512), dim3(256), 0, stream, W, W2, W3, W4);
  hipLaunchKernelGGL(k_buildN, dim3(257), dim3(256), 0, stream, W, W2, W3, W4, N, bode, cv);
  hipLaunchKernelGGL(k_pow, dim3(257), dim3(256), 0, stream, N,  N,  N4 /*N2 dst*/, slab, cv,        cv,        cv + 256);
  // NOTE: pointer names: stage outputs are N2,N4,N8; reuse distinct buffers below
  // (fix: correct destinations)
  hipLaunchKernelGGL(k_pow, dim3(257), dim3(256), 0, stream, N4, N4, N8 /*N4 dst*/, slab, cv + 256,  cv + 256,  cv + 512);
  hipLaunchKernelGGL(k_pow, dim3(257), dim3(256), 0, stream, N8, N8, N2 /*N8 dst*/, slab, cv + 512,  cv + 512,  cv + 768);
  hipLaunchKernelGGL(k_pow, dim3(257), dim3(256), 0, stream, N2, N4, (float*)nullptr, slab, cv + 768, cv + 256, cv + 1024);
  // chain check: d4: X=N,Y=N -> buf "N4" holds N^2 ; d5: X=Y=N^2 -> buf "N8" holds N^4 ;
  // d6: X=Y=N^4 -> buf "N2" holds N^8 ; d7: X=N^8, Y=N^2 -> N^10 -> slab.
  // vec chain:   d4: c2=c1@N^T+c1 (Y=N) ; d5: c4=c2@(N^2)^T+c2 (Y=N^2) ;
  //              d6: c8=c4@(N^4)^T+c4 (Y=N^4) ; d7: c10=c8@(N^2)^T+c2 (Y=N^2). OK.

  hipLaunchKernelGGL(k_main, dim3(512), dim3(256), 0, stream,
                     ids, emb, slab, c10,
                     b3, g3, be3, b4, g4, be4, b5, g5, be5, featbuf);
  hipLaunchKernelGGL(k_fin, dim3(64), dim3(64), 0, stream, featbuf, wc, bc, out);
}